// Round 16
// baseline (300.206 us; speedup 1.0000x reference)
//
#include <hip/hip_runtime.h>
#include <hip/hip_bf16.h>
#include <stdint.h>

typedef _Float16 f16x8 __attribute__((ext_vector_type(8)));
typedef _Float16 f16x2 __attribute__((ext_vector_type(2)));
typedef float f32x4 __attribute__((ext_vector_type(4)));

// All fp16 activation/weight buffers are stored ROW-SWIZZLED: within each
// 128-col chunk, element col c of row r lives at c ^ ((r&7)<<3).

__device__ __forceinline__ void gll16(const _Float16* g, _Float16* l) {
    __builtin_amdgcn_global_load_lds(
        (const __attribute__((address_space(1))) void*)g,
        (__attribute__((address_space(3))) void*)l, 16, 0, 0);
}

// ------------- weight prep: f32 [i][o] 128x128 tile -> fp16 dst[o][i^swz(o)] -------------
struct PrepDesc { const float* src; _Float16* dst; int dstride; };
struct PrepArgs { PrepDesc d[33]; };

__global__ __launch_bounds__(256) void prep_weights(PrepArgs args) {
    __shared__ _Float16 lds[128 * 129];
    const PrepDesc de = args.d[blockIdx.x];
    int t = threadIdx.x;
    for (int q = 0; q < 64; ++q) {
        int li = t + q * 256;            // linear over src [i][o]
        int i = li >> 7, o = li & 127;
        lds[o * 129 + i] = (_Float16)de.src[li];
    }
    __syncthreads();
    for (int q = 0; q < 64; ++q) {
        int lo = t + q * 256;            // linear over dst [o][i]
        int o = lo >> 7, i = lo & 127;
        de.dst[(size_t)o * de.dstride + (i ^ ((o & 7) << 3))] = lds[o * 129 + i];
    }
}

// ---- fold: W2F[v][of][640] = sum_o2 A_c[i][o2] * F_v[o2][of], fp16 swizzled output ----
// A_c: c<4 -> bases2_v[c] ([i][o2]); c==4 -> loopw2_v. F_v[o2][of] = fw[(v*128+o2)][of].
struct FoldArgs {
    const float* bases2[3];
    const float* loopw2[3];
    const float* fw;           // [384][128]
    _Float16* W2F[3];          // [128 of][640 k]
};

__global__ __launch_bounds__(256) void fold_w2f(FoldArgs fa) {
    __shared__ _Float16 As[128 * 136];
    __shared__ _Float16 Bs[128 * 136];
    int c = blockIdx.x, v = blockIdx.y, t = threadIdx.x;
    const float* A = (c < 4) ? fa.bases2[v] + (size_t)c * 16384 : fa.loopw2[v];
    for (int q = 0; q < 64; ++q) {
        int li = t + q * 256;            // i*128 + o2
        int i = li >> 7, o2 = li & 127;
        As[i * 136 + o2] = (_Float16)A[li];
    }
    for (int q = 0; q < 64; ++q) {
        int li = t + q * 256;            // o2*128 + of
        int o2 = li >> 7, of = li & 127;
        Bs[of * 136 + o2] = (_Float16)fa.fw[(size_t)(v * 128 + o2) * 128 + of];
    }
    __syncthreads();

    int wid = t >> 6, lane = t & 63;
    int wr = (wid >> 1) * 64;
    int wc = (wid & 1) * 64;
    int lm = lane & 15;
    int lk = (lane >> 4) * 8;

    f32x4 acc[4][4] = {};
    for (int ks = 0; ks < 4; ++ks) {
        f16x8 a[4], b[4];
        for (int mi = 0; mi < 4; ++mi)
            a[mi] = *(const f16x8*)(As + (wr + mi * 16 + lm) * 136 + ks * 32 + lk);
        for (int ni = 0; ni < 4; ++ni)
            b[ni] = *(const f16x8*)(Bs + (wc + ni * 16 + lm) * 136 + ks * 32 + lk);
        for (int mi = 0; mi < 4; ++mi)
            for (int ni = 0; ni < 4; ++ni)
                acc[mi][ni] = __builtin_amdgcn_mfma_f32_16x16x32_f16(a[mi], b[ni], acc[mi][ni], 0, 0, 0);
    }

    int rbase = (lane >> 4) * 4;
    _Float16* dst = fa.W2F[v];
    for (int mi = 0; mi < 4; ++mi) {
        for (int j = 0; j < 4; ++j) {
            int i = wr + mi * 16 + rbase + j;
            for (int ni = 0; ni < 4; ++ni) {
                int of = wc + ni * 16 + lm;
                dst[(size_t)of * 640 + c * 128 + (i ^ ((of & 7) << 3))] = (_Float16)acc[mi][ni][j];
            }
        }
    }
}

// bias_out[of] = fb[of] + sum_v sum_o2 b2_v[o2] * fw[(v*128+o2)][of]
__global__ __launch_bounds__(128) void fold_bias(const float* __restrict__ fb,
                                                 const float* __restrict__ fw,
                                                 const float* __restrict__ b2_0,
                                                 const float* __restrict__ b2_1,
                                                 const float* __restrict__ b2_2,
                                                 float* __restrict__ bias_out) {
    int of = threadIdx.x;
    const float* b2[3] = { b2_0, b2_1, b2_2 };
    float s = fb[of];
    for (int v = 0; v < 3; ++v)
        for (int o2 = 0; o2 < 128; ++o2)
            s += b2[v][o2] * fw[(size_t)(v * 128 + o2) * 128 + of];
    bias_out[of] = s;
}

// ---------------- f32 -> fp16 convert (row-swizzled output) ----------------
__global__ __launch_bounds__(256) void f32_to_f16(const float* __restrict__ in,
                                                  _Float16* __restrict__ out, int n4) {
    int i = blockIdx.x * 256 + threadIdx.x;
    if (i >= n4) return;
    float4 v = *((const float4*)in + i);
    int n = i >> 5;
    int c = (i & 31) * 4;
    int cs = c ^ ((n & 7) << 3);
    f16x2 a, b;
    a[0] = (_Float16)v.x; a[1] = (_Float16)v.y;
    b[0] = (_Float16)v.z; b[1] = (_Float16)v.w;
    _Float16* o = out + (size_t)n * 128 + cs;
    *(f16x2*)o = a;
    *(f16x2*)(o + 2) = b;
}

// ---------------- CSR build via block-local counting sort (no global atomics) ----------
struct EdgeArgs {
    const int* src[3]; const int* dst[3]; const int* rel[3];
    int E[3]; int N;
};

__global__ __launch_bounds__(256) void bhist(EdgeArgs ea, int* __restrict__ hmat, int nbk) {
    __shared__ int cnt[256];
    int v = blockIdx.y, blk = blockIdx.x, t = threadIdx.x;
    cnt[t] = 0;
    __syncthreads();
    int E = ea.E[v];
    const int* dst = ea.dst[v];
    int chunk = (E + 63) >> 6;
    int e0 = blk * chunk;
    int e1 = min(e0 + chunk, E);
    for (int e = e0 + t; e < e1; e += 256)
        atomicAdd(&cnt[dst[e] >> 8], 1);
    __syncthreads();
    if (t < nbk)
        hmat[((size_t)v * nbk + t) * 64 + blk] = cnt[t];
}

__global__ __launch_bounds__(256) void scan1_kernel(const int* __restrict__ deg,
                                                    int* __restrict__ off,
                                                    int* __restrict__ bsum, int n) {
    __shared__ int s[256];
    int b = blockIdx.x, t = threadIdx.x;
    int base = b * 2048 + t * 8;
    int v[8]; int sum = 0;
    for (int j = 0; j < 8; ++j) {
        int x = (base + j < n) ? deg[base + j] : 0;
        v[j] = sum;
        sum += x;
    }
    s[t] = sum;
    __syncthreads();
    for (int st = 1; st < 256; st <<= 1) {
        int y = (t >= st) ? s[t - st] : 0;
        __syncthreads();
        s[t] += y;
        __syncthreads();
    }
    int texcl = t ? s[t - 1] : 0;
    if (t == 255) bsum[b] = s[255];
    for (int j = 0; j < 8; ++j)
        if (base + j < n) off[base + j] = texcl + v[j];
}

__global__ __launch_bounds__(256) void scan2b(int* __restrict__ off,
                                              const int* __restrict__ bsum,
                                              int n, int Etot) {
    __shared__ int pref;
    int b = blockIdx.x, t = threadIdx.x;
    if (t == 0) { int p = 0; for (int j = 0; j < b; ++j) p += bsum[j]; pref = p; }
    __syncthreads();
    int p = pref;
    int base = b * 2048 + t * 8;
    for (int j = 0; j < 8; ++j)
        if (base + j < n) off[base + j] += p;
    if (b == 0 && t == 0) off[n] = Etot;
}

// mid record: src (16b) | rel (4b @16) | dst&255 (8b @20)
__global__ __launch_bounds__(256) void bscat(EdgeArgs ea, const int* __restrict__ smat,
                                             int* __restrict__ mid, int nbk) {
    __shared__ int cur[256];
    int v = blockIdx.y, blk = blockIdx.x, t = threadIdx.x;
    if (t < nbk) cur[t] = smat[((size_t)v * nbk + t) * 64 + blk];
    __syncthreads();
    int E = ea.E[v];
    const int* src = ea.src[v];
    const int* dst = ea.dst[v];
    const int* rel = ea.rel[v];
    int chunk = (E + 63) >> 6;
    int e0 = blk * chunk;
    int e1 = min(e0 + chunk, E);
    for (int e = e0 + t; e < e1; e += 256) {
        int d = dst[e];
        int pos = atomicAdd(&cur[d >> 8], 1);
        mid[pos] = src[e] | (rel[e] << 16) | ((d & 255) << 20);
    }
}

__global__ __launch_bounds__(256) void bfinal(const int* __restrict__ smat,
                                              const int* __restrict__ mid,
                                              int* __restrict__ off3,
                                              int* __restrict__ packed3,
                                              int M, int nbk, int Etot) {
    __shared__ int cnt[256];
    __shared__ int s[256];
    __shared__ int cur[256];
    int bk = blockIdx.x, v = blockIdx.y, t = threadIdx.x;
    int flat0 = (v * nbk + bk) * 64;
    int start = smat[flat0];
    int end   = smat[flat0 + 64];
    cnt[t] = 0;
    __syncthreads();
    for (int i = start + t; i < end; i += 256)
        atomicAdd(&cnt[(mid[i] >> 20) & 255], 1);
    __syncthreads();
    s[t] = cnt[t];
    __syncthreads();
    for (int st = 1; st < 256; st <<= 1) {
        int y = (t >= st) ? s[t - st] : 0;
        __syncthreads();
        s[t] += y;
        __syncthreads();
    }
    int excl = t ? s[t - 1] : 0;
    int node = (bk << 8) + t;
    if (node < M) off3[(size_t)v * M + node] = start + excl;
    cur[t] = start + excl;
    __syncthreads();
    for (int i = start + t; i < end; i += 256) {
        int m = mid[i];
        int pos = atomicAdd(&cur[(m >> 20) & 255], 1);
        packed3[pos] = (m & 0xFFFF) | (((m >> 16) & 15) << 20);
    }
    if (v == 2 && bk == nbk - 1 && t == 0) off3[(size_t)3 * M] = Etot;
}

// ---- gather: T[v][d][b][:] += coef*h[src]; 2 nodes per wave, interleaved 2+2 batches ----
struct GatherArgs {
    const int* off3;
    const int* packed3;
    const float* coef[3];     // [R][4]
    const _Float16* h[3];     // [N][128] swizzled
    _Float16* T;              // [N][4][128] swizzled per node
    int N; size_t Tvs;
};

__global__ __launch_bounds__(256) void gather3(GatherArgs g) {
    int v = blockIdx.y;
    int wid = threadIdx.x >> 6;
    int lane = threadIdx.x & 63;
    int nodeA = blockIdx.x * 8 + wid * 2;
    if (nodeA >= g.N) return;
    int nodeB = nodeA + 1;
    bool hasB = nodeB < g.N;

    const int* off = g.off3 + (size_t)v * g.N;
    const float* coef = g.coef[v];
    const _Float16* h = g.h[v];
    _Float16* T = g.T + (size_t)v * g.Tvs;

    int iA = __builtin_amdgcn_readfirstlane(off[nodeA]);
    int eA = __builtin_amdgcn_readfirstlane(off[nodeA + 1]);
    int iB = eA;
    int eB = hasB ? __builtin_amdgcn_readfirstlane(off[nodeB + 1]) : eA;

    float accA[8] = {}, accB[8] = {};

    auto edge1 = [&](int p, float* acc) {
        int s = p & 0xFFFFF, r = p >> 20;
        uint32_t q = ((const uint32_t*)(h + (size_t)s * 128))[lane ^ ((s & 7) << 2)];
        float4 c = *(const float4*)(coef + (size_t)r * 4);
        f16x2 u = __builtin_bit_cast(f16x2, q);
        float lo = (float)u[0], hi = (float)u[1];
        acc[0] += c.x * lo;  acc[1] += c.x * hi;
        acc[2] += c.y * lo;  acc[3] += c.y * hi;
        acc[4] += c.z * lo;  acc[5] += c.z * hi;
        acc[6] += c.w * lo;  acc[7] += c.w * hi;
    };

    for (; iA + 1 < eA && iB + 1 < eB; iA += 2, iB += 2) {
        int pA0 = __builtin_amdgcn_readfirstlane(g.packed3[iA]);
        int pA1 = __builtin_amdgcn_readfirstlane(g.packed3[iA + 1]);
        int pB0 = __builtin_amdgcn_readfirstlane(g.packed3[iB]);
        int pB1 = __builtin_amdgcn_readfirstlane(g.packed3[iB + 1]);
        int sA0 = pA0 & 0xFFFFF, sA1 = pA1 & 0xFFFFF;
        int sB0 = pB0 & 0xFFFFF, sB1 = pB1 & 0xFFFFF;
        uint32_t qA0 = ((const uint32_t*)(h + (size_t)sA0 * 128))[lane ^ ((sA0 & 7) << 2)];
        uint32_t qA1 = ((const uint32_t*)(h + (size_t)sA1 * 128))[lane ^ ((sA1 & 7) << 2)];
        uint32_t qB0 = ((const uint32_t*)(h + (size_t)sB0 * 128))[lane ^ ((sB0 & 7) << 2)];
        uint32_t qB1 = ((const uint32_t*)(h + (size_t)sB1 * 128))[lane ^ ((sB1 & 7) << 2)];
        float4 cA0 = *(const float4*)(coef + (size_t)(pA0 >> 20) * 4);
        float4 cA1 = *(const float4*)(coef + (size_t)(pA1 >> 20) * 4);
        float4 cB0 = *(const float4*)(coef + (size_t)(pB0 >> 20) * 4);
        float4 cB1 = *(const float4*)(coef + (size_t)(pB1 >> 20) * 4);
        f16x2 u;
        float lo, hi;
        u = __builtin_bit_cast(f16x2, qA0); lo = (float)u[0]; hi = (float)u[1];
        accA[0] += cA0.x * lo; accA[1] += cA0.x * hi; accA[2] += cA0.y * lo; accA[3] += cA0.y * hi;
        accA[4] += cA0.z * lo; accA[5] += cA0.z * hi; accA[6] += cA0.w * lo; accA[7] += cA0.w * hi;
        u = __builtin_bit_cast(f16x2, qA1); lo = (float)u[0]; hi = (float)u[1];
        accA[0] += cA1.x * lo; accA[1] += cA1.x * hi; accA[2] += cA1.y * lo; accA[3] += cA1.y * hi;
        accA[4] += cA1.z * lo; accA[5] += cA1.z * hi; accA[6] += cA1.w * lo; accA[7] += cA1.w * hi;
        u = __builtin_bit_cast(f16x2, qB0); lo = (float)u[0]; hi = (float)u[1];
        accB[0] += cB0.x * lo; accB[1] += cB0.x * hi; accB[2] += cB0.y * lo; accB[3] += cB0.y * hi;
        accB[4] += cB0.z * lo; accB[5] += cB0.z * hi; accB[6] += cB0.w * lo; accB[7] += cB0.w * hi;
        u = __builtin_bit_cast(f16x2, qB1); lo = (float)u[0]; hi = (float)u[1];
        accB[0] += cB1.x * lo; accB[1] += cB1.x * hi; accB[2] += cB1.y * lo; accB[3] += cB1.y * hi;
        accB[4] += cB1.z * lo; accB[5] += cB1.z * hi; accB[6] += cB1.w * lo; accB[7] += cB1.w * hi;
    }
    for (; iA + 1 < eA; iA += 2) {
        int p0 = __builtin_amdgcn_readfirstlane(g.packed3[iA]);
        int p1 = __builtin_amdgcn_readfirstlane(g.packed3[iA + 1]);
        edge1(p0, accA); edge1(p1, accA);
    }
    for (; iA < eA; ++iA)
        edge1(__builtin_amdgcn_readfirstlane(g.packed3[iA]), accA);
    for (; iB + 1 < eB; iB += 2) {
        int p0 = __builtin_amdgcn_readfirstlane(g.packed3[iB]);
        int p1 = __builtin_amdgcn_readfirstlane(g.packed3[iB + 1]);
        edge1(p0, accB); edge1(p1, accB);
    }
    for (; iB < eB; ++iB)
        edge1(__builtin_amdgcn_readfirstlane(g.packed3[iB]), accB);

    {
        int cs = (2 * lane) ^ ((nodeA & 7) << 3);
        _Float16* tb = T + (size_t)nodeA * 512 + cs;
        for (int b = 0; b < 4; ++b) {
            f16x2 o; o[0] = (_Float16)accA[2 * b]; o[1] = (_Float16)accA[2 * b + 1];
            *(f16x2*)(tb + b * 128) = o;
        }
    }
    if (hasB) {
        int cs = (2 * lane) ^ ((nodeB & 7) << 3);
        _Float16* tb = T + (size_t)nodeB * 512 + cs;
        for (int b = 0; b < 4; ++b) {
            f16x2 o; o[0] = (_Float16)accB[2 * b]; o[1] = (_Float16)accB[2 * b + 1];
            *(f16x2*)(tb + b * 128) = o;
        }
    }
}

// ---- layer-1 GEMM: h1 = relu([T | h] @ WT^T + bias), K=640, BM=64, swizzled fp16 out ----
struct GemmArgs {
    const _Float16* T;        // base; +v*Tvs (swizzled)
    const _Float16* hin[3];   // swizzled
    const _Float16* WT[3];    // [128][640] swizzled per 128-chunk
    const float* bias[3];
    _Float16* hout;           // base; +v*hovs (written swizzled)
    int M; int relu; size_t Tvs; size_t hovs;
};

__global__ __launch_bounds__(512) void gemm_layer(GemmArgs ga) {
    __shared__ _Float16 As[64 * 128];
    __shared__ _Float16 Bs[128 * 128];
    int v = blockIdx.y;
    const _Float16* Tb  = ga.T + (size_t)v * ga.Tvs;
    const _Float16* hin = ga.hin[v];
    const _Float16* BT  = ga.WT[v];
    const float* bias   = ga.bias[v];
    _Float16* out       = ga.hout + (size_t)v * ga.hovs;
    int M = ga.M;

    int tid = threadIdx.x;
    int m0 = blockIdx.x * 64;
    int wid = tid >> 6, lane = tid & 63;
    int wr = (wid >> 2) * 32;
    int wc = (wid & 3) * 32;
    int lm = lane & 15;
    int lk = (lane >> 4) * 8;
    int xm = (lm & 7) << 3;

    f32x4 acc[2][2] = {};

    for (int kb = 0; kb < 5; ++kb) {
        const _Float16* Asrc; size_t astride;
        if (kb < 4) { Asrc = Tb + (size_t)kb * 128; astride = 512; }
        else        { Asrc = hin;                   astride = 128; }
        for (int q = 0; q < 2; ++q) {
            int li = tid + q * 512;
            int r = li >> 4;
            int c = (li & 15) << 3;
            int gr = m0 + r; if (gr >= M) gr = M - 1;
            gll16(Asrc + (size_t)gr * astride + c, As + (size_t)li * 8);
        }
        for (int q = 0; q < 4; ++q) {
            int li = tid + q * 512;
            gll16(BT + (size_t)(li >> 4) * 640 + kb * 128 + ((li & 15) << 3),
                  Bs + (size_t)li * 8);
        }
        __syncthreads();

        for (int ks = 0; ks < 4; ++ks) {
            int ac = (ks * 32 + lk) ^ xm;
            f16x8 a[2], b[2];
            for (int mi = 0; mi < 2; ++mi)
                a[mi] = *(const f16x8*)(As + (wr + mi * 16 + lm) * 128 + ac);
            for (int ni = 0; ni < 2; ++ni)
                b[ni] = *(const f16x8*)(Bs + (wc + ni * 16 + lm) * 128 + ac);
            for (int mi = 0; mi < 2; ++mi)
                for (int ni = 0; ni < 2; ++ni)
                    acc[mi][ni] = __builtin_amdgcn_mfma_f32_16x16x32_f16(a[mi], b[ni], acc[mi][ni], 0, 0, 0);
        }
        __syncthreads();
    }

    int rbase = (lane >> 4) * 4;
    for (int mi = 0; mi < 2; ++mi) {
        for (int j = 0; j < 4; ++j) {
            int gr = m0 + wr + mi * 16 + rbase + j;
            if (gr >= M) continue;
            int rs = (gr & 7) << 3;
            for (int ni = 0; ni < 2; ++ni) {
                int col = wc + ni * 16 + lm;
                float val = acc[mi][ni][j] + bias[col];
                if (ga.relu) val = fmaxf(val, 0.f);
                out[(size_t)gr * 128 + (col ^ rs)] = (_Float16)val;
            }
        }
    }
}

// ---- fused layer2+fusion GEMM: out_f32 = sum_v [T_v | h1_v] @ W2F_v + bias_out ----
// K = 3 x 640 = 1920, BM=64, 8 waves; direct f32 write to d_out (unswizzled).
struct L2FArgs {
    const _Float16* T;        // T3 base (swizzled); +v*Tvs
    const _Float16* h1;       // h1b base (swizzled); +v*hvs
    const _Float16* W2F[3];   // [128 of][640 k] swizzled per 128-chunk
    const float* bias;        // folded bias [128]
    float* out; int M; size_t Tvs; size_t hvs;
};

__global__ __launch_bounds__(512) void gemm_l2f(L2FArgs ga) {
    __shared__ _Float16 As[64 * 128];
    __shared__ _Float16 Bs[128 * 128];
    int M = ga.M;
    int tid = threadIdx.x;
    int m0 = blockIdx.x * 64;
    int wid = tid >> 6, lane = tid & 63;
    int wr = (wid >> 2) * 32;
    int wc = (wid & 3) * 32;
    int lm = lane & 15;
    int lk = (lane >> 4) * 8;
    int xm = (lm & 7) << 3;

    f32x4 acc[2][2] = {};

    for (int v = 0; v < 3; ++v) {
        const _Float16* Tb = ga.T + (size_t)v * ga.Tvs;
        const _Float16* hb = ga.h1 + (size_t)v * ga.hvs;
        const _Float16* BT = ga.W2F[v];
        for (int kb = 0; kb < 5; ++kb) {
            const _Float16* Asrc; size_t astride;
            if (kb < 4) { Asrc = Tb + (size_t)kb * 128; astride = 512; }
            else        { Asrc = hb;                    astride = 128; }
            for (int q = 0; q < 2; ++q) {
                int li = tid + q * 512;
                int r = li >> 4;
                int c = (li & 15) << 3;
                int gr = m0 + r; if (gr >= M) gr = M - 1;
                gll16(Asrc + (size_t)gr * astride + c, As + (size_t)li * 8);
            }
            for (int q = 0; q < 4; ++q) {
                int li = tid + q * 512;
                gll16(BT + (size_t)(li >> 4) * 640 + kb * 128 + ((li & 15) << 3),
                      Bs + (size_t)li * 8);
            }
            __syncthreads();

            for (int ks = 0; ks < 4; ++ks) {
                int ac = (ks * 32 + lk) ^ xm;
                f16x8 a[2], b[2];
                for (int mi = 0; mi < 2; ++mi)
                    a[mi] = *(const f16x8*)(As + (wr + mi * 16 + lm) * 128 + ac);
                for (int ni = 0; ni < 2; ++ni)
                    b[ni] = *(const f16x8*)(Bs + (wc + ni * 16 + lm) * 128 + ac);
                for (int mi = 0; mi < 2; ++mi)
                    for (int ni = 0; ni < 2; ++ni)
                        acc[mi][ni] = __builtin_amdgcn_mfma_f32_16x16x32_f16(a[mi], b[ni], acc[mi][ni], 0, 0, 0);
            }
            __syncthreads();
        }
    }

    int rbase = (lane >> 4) * 4;
    for (int mi = 0; mi < 2; ++mi) {
        for (int j = 0; j < 4; ++j) {
            int gr = m0 + wr + mi * 16 + rbase + j;
            if (gr >= M) continue;
            for (int ni = 0; ni < 2; ++ni) {
                int col = wc + ni * 16 + lm;
                ga.out[(size_t)gr * 128 + col] = acc[mi][ni][j] + ga.bias[col];
            }
        }
    }
}

// ---------------- host launch ----------------
extern "C" void kernel_launch(void* const* d_in, const int* in_sizes, int n_in,
                              void* d_out, int out_size, void* d_ws, size_t ws_size,
                              hipStream_t stream) {
    const int D = 128;
    const int M = in_sizes[0] / D;

    struct ViewIn {
        const int *src, *dst, *rel;
        const float *bases1, *coef1, *loopw1, *bias1;
        const float *bases2, *coef2, *loopw2, *bias2;
        int E;
    } V[3];
    int idx = 1;
    for (int v = 0; v < 3; ++v) {
        V[v].src    = (const int*)d_in[idx + 0];
        V[v].dst    = (const int*)d_in[idx + 1];
        V[v].rel    = (const int*)d_in[idx + 2];
        V[v].bases1 = (const float*)d_in[idx + 3];
        V[v].coef1  = (const float*)d_in[idx + 4];
        V[v].loopw1 = (const float*)d_in[idx + 5];
        V[v].bias1  = (const float*)d_in[idx + 6];
        V[v].bases2 = (const float*)d_in[idx + 7];
        V[v].coef2  = (const float*)d_in[idx + 8];
        V[v].loopw2 = (const float*)d_in[idx + 9];
        V[v].bias2  = (const float*)d_in[idx + 10];
        V[v].E      = in_sizes[idx + 0];
        idx += 11;
    }
    const float* fusion_w = (const float*)d_in[idx];
    const float* fusion_b = (const float*)d_in[idx + 1];
    int Etot = V[0].E + V[1].E + V[2].E;

    int nbk = (M + 255) >> 8;
    int nsc = 3 * nbk * 64;

    // ---- workspace carve ----
    char* w = (char*)d_ws;
    auto alloc = [&](size_t bytes) -> char* {
        char* p = w; w += (bytes + 255) & ~(size_t)255; return p;
    };
    _Float16* nf16 = (_Float16*)alloc((size_t)M * 128 * 2);
    _Float16* wts  = (_Float16*)alloc((size_t)(3 * 81920) * 2);      // layer-1 WT only
    _Float16* w2f  = (_Float16*)alloc((size_t)(3 * 81920) * 2);      // folded W2@F
    float* bias_o  = (float*)alloc(128 * 4);
    int* hmat      = (int*)alloc((size_t)nsc * 4);
    int* smat      = (int*)alloc(((size_t)nsc + 1) * 4);
    int* bsum      = (int*)alloc(512);
    int* off3      = (int*)alloc(((size_t)3 * M + 1) * 4);
    int* mid       = (int*)alloc((size_t)Etot * 4);
    int* packed3   = (int*)alloc((size_t)Etot * 4);
    _Float16* T3   = (_Float16*)alloc((size_t)3 * M * 512 * 2);
    _Float16* h1b  = (_Float16*)alloc((size_t)3 * M * 128 * 2);

    _Float16 *WT1[3], *W2F[3];
    for (int v = 0; v < 3; ++v) {
        WT1[v] = wts + (size_t)v * 81920;
        W2F[v] = w2f + (size_t)v * 81920;
    }

    // ---- prep: layer-1 weight transposes (15 tiles) ----
    PrepArgs pa;
    int t = 0;
    for (int v = 0; v < 3; ++v) {
        for (int b = 0; b < 4; ++b) {
            pa.d[t].src = V[v].bases1 + (size_t)b * 16384;
            pa.d[t].dst = WT1[v] + (size_t)b * 128;
            pa.d[t].dstride = 640; ++t;
        }
        pa.d[t].src = V[v].loopw1;
        pa.d[t].dst = WT1[v] + 512;
        pa.d[t].dstride = 640; ++t;
    }
    prep_weights<<<t, 256, 0, stream>>>(pa);

    // ---- fold W2@F and bias ----
    FoldArgs fo;
    for (int v = 0; v < 3; ++v) {
        fo.bases2[v] = V[v].bases2;
        fo.loopw2[v] = V[v].loopw2;
        fo.W2F[v] = W2F[v];
    }
    fo.fw = fusion_w;
    fold_w2f<<<dim3(5, 3), 256, 0, stream>>>(fo);
    fold_bias<<<1, 128, 0, stream>>>(fusion_b, fusion_w,
                                     V[0].bias2, V[1].bias2, V[2].bias2, bias_o);

    int n4 = M * D / 4;
    f32_to_f16<<<(n4 + 255) / 256, 256, 0, stream>>>((const float*)d_in[0], nf16, n4);

    // ---- CSR build (block-local counting sort) ----
    EdgeArgs ea;
    for (int v = 0; v < 3; ++v) {
        ea.src[v] = V[v].src; ea.dst[v] = V[v].dst; ea.rel[v] = V[v].rel; ea.E[v] = V[v].E;
    }
    ea.N = M;
    int nsb = (nsc + 2047) / 2048;
    bhist<<<dim3(64, 3), 256, 0, stream>>>(ea, hmat, nbk);
    scan1_kernel<<<nsb, 256, 0, stream>>>(hmat, smat, bsum, nsc);
    scan2b<<<nsb, 256, 0, stream>>>(smat, bsum, nsc, Etot);
    bscat<<<dim3(64, 3), 256, 0, stream>>>(ea, smat, mid, nbk);
    bfinal<<<dim3(nbk, 3), 256, 0, stream>>>(smat, mid, off3, packed3, M, nbk, Etot);

    int ng  = (M + 7) / 8;
    int gxL = (M + 63) / 64;
    size_t Tvs = (size_t)M * 512;
    size_t hvs = (size_t)M * 128;
    float* outF = (float*)d_out;

    // ---- layer 1 ----
    GatherArgs g1;
    g1.off3 = off3; g1.packed3 = packed3; g1.T = T3; g1.N = M; g1.Tvs = Tvs;
    for (int v = 0; v < 3; ++v) { g1.coef[v] = V[v].coef1; g1.h[v] = nf16; }
    gather3<<<dim3(ng, 3), 256, 0, stream>>>(g1);

    GemmArgs m1;
    m1.T = T3; m1.hout = h1b; m1.M = M; m1.relu = 1; m1.Tvs = Tvs; m1.hovs = hvs;
    for (int v = 0; v < 3; ++v) { m1.hin[v] = nf16; m1.WT[v] = WT1[v]; m1.bias[v] = V[v].bias1; }
    gemm_layer<<<dim3(gxL, 3), 512, 0, stream>>>(m1);

    // ---- layer 2 gather ----
    GatherArgs g2 = g1;
    for (int v = 0; v < 3; ++v) { g2.coef[v] = V[v].coef2; g2.h[v] = h1b + (size_t)v * hvs; }
    gather3<<<dim3(ng, 3), 256, 0, stream>>>(g2);

    // ---- fused layer2 + fusion ----
    L2FArgs l2;
    l2.T = T3; l2.h1 = h1b; l2.bias = bias_o; l2.out = outF;
    l2.M = M; l2.Tvs = Tvs; l2.hvs = hvs;
    for (int v = 0; v < 3; ++v) l2.W2F[v] = W2F[v];
    gemm_l2f<<<gxL, 512, 0, stream>>>(l2);
}

// Round 17
// 290.730 us; speedup vs baseline: 1.0326x; 1.0326x over previous
//
#include <hip/hip_runtime.h>
#include <hip/hip_bf16.h>
#include <stdint.h>

typedef _Float16 f16x8 __attribute__((ext_vector_type(8)));
typedef _Float16 f16x2 __attribute__((ext_vector_type(2)));
typedef float f32x4 __attribute__((ext_vector_type(4)));

// All fp16 activation/weight buffers are stored ROW-SWIZZLED: within each
// 128-col chunk, element col c of row r lives at c ^ ((r&7)<<3).

__device__ __forceinline__ void gll16(const _Float16* g, _Float16* l) {
    __builtin_amdgcn_global_load_lds(
        (const __attribute__((address_space(1))) void*)g,
        (__attribute__((address_space(3))) void*)l, 16, 0, 0);
}

// ------------- weight prep: f32 [i][o] 128x128 tile -> fp16 dst[o][i^swz(o)] -------------
struct PrepDesc { const float* src; _Float16* dst; int dstride; };
struct PrepArgs { PrepDesc d[33]; };

__global__ __launch_bounds__(256) void prep_weights(PrepArgs args) {
    __shared__ _Float16 lds[128 * 129];
    const PrepDesc de = args.d[blockIdx.x];
    int t = threadIdx.x;
    for (int q = 0; q < 64; ++q) {
        int li = t + q * 256;            // linear over src [i][o]
        int i = li >> 7, o = li & 127;
        lds[o * 129 + i] = (_Float16)de.src[li];
    }
    __syncthreads();
    for (int q = 0; q < 64; ++q) {
        int lo = t + q * 256;            // linear over dst [o][i]
        int o = lo >> 7, i = lo & 127;
        de.dst[(size_t)o * de.dstride + (i ^ ((o & 7) << 3))] = lds[o * 129 + i];
    }
}

// ---- fold: W2F[v][of][640] = sum_o2 A_c[i][o2] * F_v[o2][of], fp16 swizzled output ----
struct FoldArgs {
    const float* bases2[3];
    const float* loopw2[3];
    const float* fw;           // [384][128]
    _Float16* W2F[3];          // [128 of][640 k]
};

__global__ __launch_bounds__(256) void fold_w2f(FoldArgs fa) {
    __shared__ _Float16 As[128 * 136];
    __shared__ _Float16 Bs[128 * 136];
    int c = blockIdx.x, v = blockIdx.y, t = threadIdx.x;
    const float* A = (c < 4) ? fa.bases2[v] + (size_t)c * 16384 : fa.loopw2[v];
    for (int q = 0; q < 64; ++q) {
        int li = t + q * 256;            // i*128 + o2
        int i = li >> 7, o2 = li & 127;
        As[i * 136 + o2] = (_Float16)A[li];
    }
    for (int q = 0; q < 64; ++q) {
        int li = t + q * 256;            // o2*128 + of
        int o2 = li >> 7, of = li & 127;
        Bs[of * 136 + o2] = (_Float16)fa.fw[(size_t)(v * 128 + o2) * 128 + of];
    }
    __syncthreads();

    int wid = t >> 6, lane = t & 63;
    int wr = (wid >> 1) * 64;
    int wc = (wid & 1) * 64;
    int lm = lane & 15;
    int lk = (lane >> 4) * 8;

    f32x4 acc[4][4] = {};
    for (int ks = 0; ks < 4; ++ks) {
        f16x8 a[4], b[4];
        for (int mi = 0; mi < 4; ++mi)
            a[mi] = *(const f16x8*)(As + (wr + mi * 16 + lm) * 136 + ks * 32 + lk);
        for (int ni = 0; ni < 4; ++ni)
            b[ni] = *(const f16x8*)(Bs + (wc + ni * 16 + lm) * 136 + ks * 32 + lk);
        for (int mi = 0; mi < 4; ++mi)
            for (int ni = 0; ni < 4; ++ni)
                acc[mi][ni] = __builtin_amdgcn_mfma_f32_16x16x32_f16(a[mi], b[ni], acc[mi][ni], 0, 0, 0);
    }

    int rbase = (lane >> 4) * 4;
    _Float16* dst = fa.W2F[v];
    for (int mi = 0; mi < 4; ++mi) {
        for (int j = 0; j < 4; ++j) {
            int i = wr + mi * 16 + rbase + j;
            for (int ni = 0; ni < 4; ++ni) {
                int of = wc + ni * 16 + lm;
                dst[(size_t)of * 640 + c * 128 + (i ^ ((of & 7) << 3))] = (_Float16)acc[mi][ni][j];
            }
        }
    }
}

// bias_out[of] = fb[of] + sum_{j<384} b2[j/128][j%128] * fw[j*128+of]
// one block per of; 128 threads each sum 3 terms, LDS tree reduce.
__global__ __launch_bounds__(128) void fold_bias(const float* __restrict__ fb,
                                                 const float* __restrict__ fw,
                                                 const float* __restrict__ b2_0,
                                                 const float* __restrict__ b2_1,
                                                 const float* __restrict__ b2_2,
                                                 float* __restrict__ bias_out) {
    __shared__ float s[128];
    int of = blockIdx.x, t = threadIdx.x;
    const float* b2[3] = { b2_0, b2_1, b2_2 };
    float acc = 0.f;
    for (int k = 0; k < 3; ++k) {
        int j = t + k * 128;             // j = v*128 + o2 with v=k (since blocks of 128)
        acc += b2[k][t] * fw[(size_t)j * 128 + of];
    }
    s[t] = acc;
    __syncthreads();
    for (int st = 64; st > 0; st >>= 1) {
        if (t < st) s[t] += s[t + st];
        __syncthreads();
    }
    if (t == 0) bias_out[of] = fb[of] + s[0];
}

// ---------------- f32 -> fp16 convert (row-swizzled output) ----------------
__global__ __launch_bounds__(256) void f32_to_f16(const float* __restrict__ in,
                                                  _Float16* __restrict__ out, int n4) {
    int i = blockIdx.x * 256 + threadIdx.x;
    if (i >= n4) return;
    float4 v = *((const float4*)in + i);
    int n = i >> 5;
    int c = (i & 31) * 4;
    int cs = c ^ ((n & 7) << 3);
    f16x2 a, b;
    a[0] = (_Float16)v.x; a[1] = (_Float16)v.y;
    b[0] = (_Float16)v.z; b[1] = (_Float16)v.w;
    _Float16* o = out + (size_t)n * 128 + cs;
    *(f16x2*)o = a;
    *(f16x2*)(o + 2) = b;
}

// ---------------- CSR build via block-local counting sort (no global atomics) ----------
struct EdgeArgs {
    const int* src[3]; const int* dst[3]; const int* rel[3];
    int E[3]; int N;
};

__global__ __launch_bounds__(256) void bhist(EdgeArgs ea, int* __restrict__ hmat, int nbk) {
    __shared__ int cnt[256];
    int v = blockIdx.y, blk = blockIdx.x, t = threadIdx.x;
    cnt[t] = 0;
    __syncthreads();
    int E = ea.E[v];
    const int* dst = ea.dst[v];
    int chunk = (E + 63) >> 6;
    int e0 = blk * chunk;
    int e1 = min(e0 + chunk, E);
    for (int e = e0 + t; e < e1; e += 256)
        atomicAdd(&cnt[dst[e] >> 8], 1);
    __syncthreads();
    if (t < nbk)
        hmat[((size_t)v * nbk + t) * 64 + blk] = cnt[t];
}

__global__ __launch_bounds__(256) void scan1_kernel(const int* __restrict__ deg,
                                                    int* __restrict__ off,
                                                    int* __restrict__ bsum, int n) {
    __shared__ int s[256];
    int b = blockIdx.x, t = threadIdx.x;
    int base = b * 2048 + t * 8;
    int v[8]; int sum = 0;
    for (int j = 0; j < 8; ++j) {
        int x = (base + j < n) ? deg[base + j] : 0;
        v[j] = sum;
        sum += x;
    }
    s[t] = sum;
    __syncthreads();
    for (int st = 1; st < 256; st <<= 1) {
        int y = (t >= st) ? s[t - st] : 0;
        __syncthreads();
        s[t] += y;
        __syncthreads();
    }
    int texcl = t ? s[t - 1] : 0;
    if (t == 255) bsum[b] = s[255];
    for (int j = 0; j < 8; ++j)
        if (base + j < n) off[base + j] = texcl + v[j];
}

__global__ __launch_bounds__(256) void scan2b(int* __restrict__ off,
                                              const int* __restrict__ bsum,
                                              int n, int Etot) {
    __shared__ int pref;
    int b = blockIdx.x, t = threadIdx.x;
    if (t == 0) { int p = 0; for (int j = 0; j < b; ++j) p += bsum[j]; pref = p; }
    __syncthreads();
    int p = pref;
    int base = b * 2048 + t * 8;
    for (int j = 0; j < 8; ++j)
        if (base + j < n) off[base + j] += p;
    if (b == 0 && t == 0) off[n] = Etot;
}

// mid record: src (16b) | rel (4b @16) | dst&255 (8b @20)
__global__ __launch_bounds__(256) void bscat(EdgeArgs ea, const int* __restrict__ smat,
                                             int* __restrict__ mid, int nbk) {
    __shared__ int cur[256];
    int v = blockIdx.y, blk = blockIdx.x, t = threadIdx.x;
    if (t < nbk) cur[t] = smat[((size_t)v * nbk + t) * 64 + blk];
    __syncthreads();
    int E = ea.E[v];
    const int* src = ea.src[v];
    const int* dst = ea.dst[v];
    const int* rel = ea.rel[v];
    int chunk = (E + 63) >> 6;
    int e0 = blk * chunk;
    int e1 = min(e0 + chunk, E);
    for (int e = e0 + t; e < e1; e += 256) {
        int d = dst[e];
        int pos = atomicAdd(&cur[d >> 8], 1);
        mid[pos] = src[e] | (rel[e] << 16) | ((d & 255) << 20);
    }
}

__global__ __launch_bounds__(256) void bfinal(const int* __restrict__ smat,
                                              const int* __restrict__ mid,
                                              int* __restrict__ off3,
                                              int* __restrict__ packed3,
                                              int M, int nbk, int Etot) {
    __shared__ int cnt[256];
    __shared__ int s[256];
    __shared__ int cur[256];
    int bk = blockIdx.x, v = blockIdx.y, t = threadIdx.x;
    int flat0 = (v * nbk + bk) * 64;
    int start = smat[flat0];
    int end   = smat[flat0 + 64];
    cnt[t] = 0;
    __syncthreads();
    for (int i = start + t; i < end; i += 256)
        atomicAdd(&cnt[(mid[i] >> 20) & 255], 1);
    __syncthreads();
    s[t] = cnt[t];
    __syncthreads();
    for (int st = 1; st < 256; st <<= 1) {
        int y = (t >= st) ? s[t - st] : 0;
        __syncthreads();
        s[t] += y;
        __syncthreads();
    }
    int excl = t ? s[t - 1] : 0;
    int node = (bk << 8) + t;
    if (node < M) off3[(size_t)v * M + node] = start + excl;
    cur[t] = start + excl;
    __syncthreads();
    for (int i = start + t; i < end; i += 256) {
        int m = mid[i];
        int pos = atomicAdd(&cur[(m >> 20) & 255], 1);
        packed3[pos] = (m & 0xFFFF) | (((m >> 16) & 15) << 20);
    }
    if (v == 2 && bk == nbk - 1 && t == 0) off3[(size_t)3 * M] = Etot;
}

// ---- gather: T[v][d][b][:] += coef*h[src]; 2 nodes per wave, interleaved 2+2 batches ----
struct GatherArgs {
    const int* off3;
    const int* packed3;
    const float* coef[3];     // [R][4]
    const _Float16* h[3];     // [N][128] swizzled
    _Float16* T;              // [N][4][128] swizzled per node
    int N; size_t Tvs;
};

__global__ __launch_bounds__(256) void gather3(GatherArgs g) {
    int v = blockIdx.y;
    int wid = threadIdx.x >> 6;
    int lane = threadIdx.x & 63;
    int nodeA = blockIdx.x * 8 + wid * 2;
    if (nodeA >= g.N) return;
    int nodeB = nodeA + 1;
    bool hasB = nodeB < g.N;

    const int* off = g.off3 + (size_t)v * g.N;
    const float* coef = g.coef[v];
    const _Float16* h = g.h[v];
    _Float16* T = g.T + (size_t)v * g.Tvs;

    int iA = __builtin_amdgcn_readfirstlane(off[nodeA]);
    int eA = __builtin_amdgcn_readfirstlane(off[nodeA + 1]);
    int iB = eA;
    int eB = hasB ? __builtin_amdgcn_readfirstlane(off[nodeB + 1]) : eA;

    float accA[8] = {}, accB[8] = {};

    auto edge1 = [&](int p, float* acc) {
        int s = p & 0xFFFFF, r = p >> 20;
        uint32_t q = ((const uint32_t*)(h + (size_t)s * 128))[lane ^ ((s & 7) << 2)];
        float4 c = *(const float4*)(coef + (size_t)r * 4);
        f16x2 u = __builtin_bit_cast(f16x2, q);
        float lo = (float)u[0], hi = (float)u[1];
        acc[0] += c.x * lo;  acc[1] += c.x * hi;
        acc[2] += c.y * lo;  acc[3] += c.y * hi;
        acc[4] += c.z * lo;  acc[5] += c.z * hi;
        acc[6] += c.w * lo;  acc[7] += c.w * hi;
    };

    for (; iA + 1 < eA && iB + 1 < eB; iA += 2, iB += 2) {
        int pA0 = __builtin_amdgcn_readfirstlane(g.packed3[iA]);
        int pA1 = __builtin_amdgcn_readfirstlane(g.packed3[iA + 1]);
        int pB0 = __builtin_amdgcn_readfirstlane(g.packed3[iB]);
        int pB1 = __builtin_amdgcn_readfirstlane(g.packed3[iB + 1]);
        int sA0 = pA0 & 0xFFFFF, sA1 = pA1 & 0xFFFFF;
        int sB0 = pB0 & 0xFFFFF, sB1 = pB1 & 0xFFFFF;
        uint32_t qA0 = ((const uint32_t*)(h + (size_t)sA0 * 128))[lane ^ ((sA0 & 7) << 2)];
        uint32_t qA1 = ((const uint32_t*)(h + (size_t)sA1 * 128))[lane ^ ((sA1 & 7) << 2)];
        uint32_t qB0 = ((const uint32_t*)(h + (size_t)sB0 * 128))[lane ^ ((sB0 & 7) << 2)];
        uint32_t qB1 = ((const uint32_t*)(h + (size_t)sB1 * 128))[lane ^ ((sB1 & 7) << 2)];
        float4 cA0 = *(const float4*)(coef + (size_t)(pA0 >> 20) * 4);
        float4 cA1 = *(const float4*)(coef + (size_t)(pA1 >> 20) * 4);
        float4 cB0 = *(const float4*)(coef + (size_t)(pB0 >> 20) * 4);
        float4 cB1 = *(const float4*)(coef + (size_t)(pB1 >> 20) * 4);
        f16x2 u;
        float lo, hi;
        u = __builtin_bit_cast(f16x2, qA0); lo = (float)u[0]; hi = (float)u[1];
        accA[0] += cA0.x * lo; accA[1] += cA0.x * hi; accA[2] += cA0.y * lo; accA[3] += cA0.y * hi;
        accA[4] += cA0.z * lo; accA[5] += cA0.z * hi; accA[6] += cA0.w * lo; accA[7] += cA0.w * hi;
        u = __builtin_bit_cast(f16x2, qA1); lo = (float)u[0]; hi = (float)u[1];
        accA[0] += cA1.x * lo; accA[1] += cA1.x * hi; accA[2] += cA1.y * lo; accA[3] += cA1.y * hi;
        accA[4] += cA1.z * lo; accA[5] += cA1.z * hi; accA[6] += cA1.w * lo; accA[7] += cA1.w * hi;
        u = __builtin_bit_cast(f16x2, qB0); lo = (float)u[0]; hi = (float)u[1];
        accB[0] += cB0.x * lo; accB[1] += cB0.x * hi; accB[2] += cB0.y * lo; accB[3] += cB0.y * hi;
        accB[4] += cB0.z * lo; accB[5] += cB0.z * hi; accB[6] += cB0.w * lo; accB[7] += cB0.w * hi;
        u = __builtin_bit_cast(f16x2, qB1); lo = (float)u[0]; hi = (float)u[1];
        accB[0] += cB1.x * lo; accB[1] += cB1.x * hi; accB[2] += cB1.y * lo; accB[3] += cB1.y * hi;
        accB[4] += cB1.z * lo; accB[5] += cB1.z * hi; accB[6] += cB1.w * lo; accB[7] += cB1.w * hi;
    }
    for (; iA + 1 < eA; iA += 2) {
        int p0 = __builtin_amdgcn_readfirstlane(g.packed3[iA]);
        int p1 = __builtin_amdgcn_readfirstlane(g.packed3[iA + 1]);
        edge1(p0, accA); edge1(p1, accA);
    }
    for (; iA < eA; ++iA)
        edge1(__builtin_amdgcn_readfirstlane(g.packed3[iA]), accA);
    for (; iB + 1 < eB; iB += 2) {
        int p0 = __builtin_amdgcn_readfirstlane(g.packed3[iB]);
        int p1 = __builtin_amdgcn_readfirstlane(g.packed3[iB + 1]);
        edge1(p0, accB); edge1(p1, accB);
    }
    for (; iB < eB; ++iB)
        edge1(__builtin_amdgcn_readfirstlane(g.packed3[iB]), accB);

    {
        int cs = (2 * lane) ^ ((nodeA & 7) << 3);
        _Float16* tb = T + (size_t)nodeA * 512 + cs;
        for (int b = 0; b < 4; ++b) {
            f16x2 o; o[0] = (_Float16)accA[2 * b]; o[1] = (_Float16)accA[2 * b + 1];
            *(f16x2*)(tb + b * 128) = o;
        }
    }
    if (hasB) {
        int cs = (2 * lane) ^ ((nodeB & 7) << 3);
        _Float16* tb = T + (size_t)nodeB * 512 + cs;
        for (int b = 0; b < 4; ++b) {
            f16x2 o; o[0] = (_Float16)accB[2 * b]; o[1] = (_Float16)accB[2 * b + 1];
            *(f16x2*)(tb + b * 128) = o;
        }
    }
}

// ---- layer-1 GEMM: h1 = relu([T | h] @ WT^T + bias), K=640, BM=64, swizzled fp16 out ----
struct GemmArgs {
    const _Float16* T;        // base; +v*Tvs (swizzled)
    const _Float16* hin[3];   // swizzled
    const _Float16* WT[3];    // [128][640] swizzled per 128-chunk
    const float* bias[3];
    _Float16* hout;           // base; +v*hovs (written swizzled)
    int M; int relu; size_t Tvs; size_t hovs;
};

__global__ __launch_bounds__(512) void gemm_layer(GemmArgs ga) {
    __shared__ _Float16 As[64 * 128];
    __shared__ _Float16 Bs[128 * 128];
    int v = blockIdx.y;
    const _Float16* Tb  = ga.T + (size_t)v * ga.Tvs;
    const _Float16* hin = ga.hin[v];
    const _Float16* BT  = ga.WT[v];
    const float* bias   = ga.bias[v];
    _Float16* out       = ga.hout + (size_t)v * ga.hovs;
    int M = ga.M;

    int tid = threadIdx.x;
    int m0 = blockIdx.x * 64;
    int wid = tid >> 6, lane = tid & 63;
    int wr = (wid >> 2) * 32;
    int wc = (wid & 3) * 32;
    int lm = lane & 15;
    int lk = (lane >> 4) * 8;
    int xm = (lm & 7) << 3;

    f32x4 acc[2][2] = {};

    for (int kb = 0; kb < 5; ++kb) {
        const _Float16* Asrc; size_t astride;
        if (kb < 4) { Asrc = Tb + (size_t)kb * 128; astride = 512; }
        else        { Asrc = hin;                   astride = 128; }
        for (int q = 0; q < 2; ++q) {
            int li = tid + q * 512;
            int r = li >> 4;
            int c = (li & 15) << 3;
            int gr = m0 + r; if (gr >= M) gr = M - 1;
            gll16(Asrc + (size_t)gr * astride + c, As + (size_t)li * 8);
        }
        for (int q = 0; q < 4; ++q) {
            int li = tid + q * 512;
            gll16(BT + (size_t)(li >> 4) * 640 + kb * 128 + ((li & 15) << 3),
                  Bs + (size_t)li * 8);
        }
        __syncthreads();

        for (int ks = 0; ks < 4; ++ks) {
            int ac = (ks * 32 + lk) ^ xm;
            f16x8 a[2], b[2];
            for (int mi = 0; mi < 2; ++mi)
                a[mi] = *(const f16x8*)(As + (wr + mi * 16 + lm) * 128 + ac);
            for (int ni = 0; ni < 2; ++ni)
                b[ni] = *(const f16x8*)(Bs + (wc + ni * 16 + lm) * 128 + ac);
            for (int mi = 0; mi < 2; ++mi)
                for (int ni = 0; ni < 2; ++ni)
                    acc[mi][ni] = __builtin_amdgcn_mfma_f32_16x16x32_f16(a[mi], b[ni], acc[mi][ni], 0, 0, 0);
        }
        __syncthreads();
    }

    int rbase = (lane >> 4) * 4;
    for (int mi = 0; mi < 2; ++mi) {
        for (int j = 0; j < 4; ++j) {
            int gr = m0 + wr + mi * 16 + rbase + j;
            if (gr >= M) continue;
            int rs = (gr & 7) << 3;
            for (int ni = 0; ni < 2; ++ni) {
                int col = wc + ni * 16 + lm;
                float val = acc[mi][ni][j] + bias[col];
                if (ga.relu) val = fmaxf(val, 0.f);
                out[(size_t)gr * 128 + (col ^ rs)] = (_Float16)val;
            }
        }
    }
}

// ---- fused layer2+fusion GEMM: out_f32 = sum_v [T_v | h1_v] @ W2F_v + bias_out ----
struct L2FArgs {
    const _Float16* T;        // T3 base (swizzled); +v*Tvs
    const _Float16* h1;       // h1b base (swizzled); +v*hvs
    const _Float16* W2F[3];   // [128 of][640 k] swizzled per 128-chunk
    const float* bias;        // folded bias [128]
    float* out; int M; size_t Tvs; size_t hvs;
};

__global__ __launch_bounds__(512) void gemm_l2f(L2FArgs ga) {
    __shared__ _Float16 As[64 * 128];
    __shared__ _Float16 Bs[128 * 128];
    int M = ga.M;
    int tid = threadIdx.x;
    int m0 = blockIdx.x * 64;
    int wid = tid >> 6, lane = tid & 63;
    int wr = (wid >> 2) * 32;
    int wc = (wid & 3) * 32;
    int lm = lane & 15;
    int lk = (lane >> 4) * 8;
    int xm = (lm & 7) << 3;

    f32x4 acc[2][2] = {};

    for (int v = 0; v < 3; ++v) {
        const _Float16* Tb = ga.T + (size_t)v * ga.Tvs;
        const _Float16* hb = ga.h1 + (size_t)v * ga.hvs;
        const _Float16* BT = ga.W2F[v];
        for (int kb = 0; kb < 5; ++kb) {
            const _Float16* Asrc; size_t astride;
            if (kb < 4) { Asrc = Tb + (size_t)kb * 128; astride = 512; }
            else        { Asrc = hb;                    astride = 128; }
            for (int q = 0; q < 2; ++q) {
                int li = tid + q * 512;
                int r = li >> 4;
                int c = (li & 15) << 3;
                int gr = m0 + r; if (gr >= M) gr = M - 1;
                gll16(Asrc + (size_t)gr * astride + c, As + (size_t)li * 8);
            }
            for (int q = 0; q < 4; ++q) {
                int li = tid + q * 512;
                gll16(BT + (size_t)(li >> 4) * 640 + kb * 128 + ((li & 15) << 3),
                      Bs + (size_t)li * 8);
            }
            __syncthreads();

            for (int ks = 0; ks < 4; ++ks) {
                int ac = (ks * 32 + lk) ^ xm;
                f16x8 a[2], b[2];
                for (int mi = 0; mi < 2; ++mi)
                    a[mi] = *(const f16x8*)(As + (wr + mi * 16 + lm) * 128 + ac);
                for (int ni = 0; ni < 2; ++ni)
                    b[ni] = *(const f16x8*)(Bs + (wc + ni * 16 + lm) * 128 + ac);
                for (int mi = 0; mi < 2; ++mi)
                    for (int ni = 0; ni < 2; ++ni)
                        acc[mi][ni] = __builtin_amdgcn_mfma_f32_16x16x32_f16(a[mi], b[ni], acc[mi][ni], 0, 0, 0);
            }
            __syncthreads();
        }
    }

    int rbase = (lane >> 4) * 4;
    for (int mi = 0; mi < 2; ++mi) {
        for (int j = 0; j < 4; ++j) {
            int gr = m0 + wr + mi * 16 + rbase + j;
            if (gr >= M) continue;
            for (int ni = 0; ni < 2; ++ni) {
                int col = wc + ni * 16 + lm;
                ga.out[(size_t)gr * 128 + col] = acc[mi][ni][j] + ga.bias[col];
            }
        }
    }
}

// ---------------- host launch ----------------
extern "C" void kernel_launch(void* const* d_in, const int* in_sizes, int n_in,
                              void* d_out, int out_size, void* d_ws, size_t ws_size,
                              hipStream_t stream) {
    const int D = 128;
    const int M = in_sizes[0] / D;

    struct ViewIn {
        const int *src, *dst, *rel;
        const float *bases1, *coef1, *loopw1, *bias1;
        const float *bases2, *coef2, *loopw2, *bias2;
        int E;
    } V[3];
    int idx = 1;
    for (int v = 0; v < 3; ++v) {
        V[v].src    = (const int*)d_in[idx + 0];
        V[v].dst    = (const int*)d_in[idx + 1];
        V[v].rel    = (const int*)d_in[idx + 2];
        V[v].bases1 = (const float*)d_in[idx + 3];
        V[v].coef1  = (const float*)d_in[idx + 4];
        V[v].loopw1 = (const float*)d_in[idx + 5];
        V[v].bias1  = (const float*)d_in[idx + 6];
        V[v].bases2 = (const float*)d_in[idx + 7];
        V[v].coef2  = (const float*)d_in[idx + 8];
        V[v].loopw2 = (const float*)d_in[idx + 9];
        V[v].bias2  = (const float*)d_in[idx + 10];
        V[v].E      = in_sizes[idx + 0];
        idx += 11;
    }
    const float* fusion_w = (const float*)d_in[idx];
    const float* fusion_b = (const float*)d_in[idx + 1];
    int Etot = V[0].E + V[1].E + V[2].E;

    int nbk = (M + 255) >> 8;
    int nsc = 3 * nbk * 64;

    // ---- workspace carve ----
    char* w = (char*)d_ws;
    auto alloc = [&](size_t bytes) -> char* {
        char* p = w; w += (bytes + 255) & ~(size_t)255; return p;
    };
    _Float16* nf16 = (_Float16*)alloc((size_t)M * 128 * 2);
    _Float16* wts  = (_Float16*)alloc((size_t)(3 * 81920) * 2);      // layer-1 WT only
    _Float16* w2f  = (_Float16*)alloc((size_t)(3 * 81920) * 2);      // folded W2@F
    float* bias_o  = (float*)alloc(128 * 4);
    int* hmat      = (int*)alloc((size_t)nsc * 4);
    int* smat      = (int*)alloc(((size_t)nsc + 1) * 4);
    int* bsum      = (int*)alloc(512);
    int* off3      = (int*)alloc(((size_t)3 * M + 1) * 4);
    int* mid       = (int*)alloc((size_t)Etot * 4);
    int* packed3   = (int*)alloc((size_t)Etot * 4);
    _Float16* T3   = (_Float16*)alloc((size_t)3 * M * 512 * 2);
    _Float16* h1b  = (_Float16*)alloc((size_t)3 * M * 128 * 2);

    _Float16 *WT1[3], *W2F[3];
    for (int v = 0; v < 3; ++v) {
        WT1[v] = wts + (size_t)v * 81920;
        W2F[v] = w2f + (size_t)v * 81920;
    }

    // ---- prep: layer-1 weight transposes (15 tiles) ----
    PrepArgs pa;
    int t = 0;
    for (int v = 0; v < 3; ++v) {
        for (int b = 0; b < 4; ++b) {
            pa.d[t].src = V[v].bases1 + (size_t)b * 16384;
            pa.d[t].dst = WT1[v] + (size_t)b * 128;
            pa.d[t].dstride = 640; ++t;
        }
        pa.d[t].src = V[v].loopw1;
        pa.d[t].dst = WT1[v] + 512;
        pa.d[t].dstride = 640; ++t;
    }
    prep_weights<<<t, 256, 0, stream>>>(pa);

    // ---- fold W2@F and bias ----
    FoldArgs fo;
    for (int v = 0; v < 3; ++v) {
        fo.bases2[v] = V[v].bases2;
        fo.loopw2[v] = V[v].loopw2;
        fo.W2F[v] = W2F[v];
    }
    fo.fw = fusion_w;
    fold_w2f<<<dim3(5, 3), 256, 0, stream>>>(fo);
    fold_bias<<<128, 128, 0, stream>>>(fusion_b, fusion_w,
                                       V[0].bias2, V[1].bias2, V[2].bias2, bias_o);

    int n4 = M * D / 4;
    f32_to_f16<<<(n4 + 255) / 256, 256, 0, stream>>>((const float*)d_in[0], nf16, n4);

    // ---- CSR build (block-local counting sort) ----
    EdgeArgs ea;
    for (int v = 0; v < 3; ++v) {
        ea.src[v] = V[v].src; ea.dst[v] = V[v].dst; ea.rel[v] = V[v].rel; ea.E[v] = V[v].E;
    }
    ea.N = M;
    int nsb = (nsc + 2047) / 2048;
    bhist<<<dim3(64, 3), 256, 0, stream>>>(ea, hmat, nbk);
    scan1_kernel<<<nsb, 256, 0, stream>>>(hmat, smat, bsum, nsc);
    scan2b<<<nsb, 256, 0, stream>>>(smat, bsum, nsc, Etot);
    bscat<<<dim3(64, 3), 256, 0, stream>>>(ea, smat, mid, nbk);
    bfinal<<<dim3(nbk, 3), 256, 0, stream>>>(smat, mid, off3, packed3, M, nbk, Etot);

    int ng  = (M + 7) / 8;
    int gxL = (M + 63) / 64;
    size_t Tvs = (size_t)M * 512;
    size_t hvs = (size_t)M * 128;
    float* outF = (float*)d_out;

    // ---- layer 1 ----
    GatherArgs g1;
    g1.off3 = off3; g1.packed3 = packed3; g1.T = T3; g1.N = M; g1.Tvs = Tvs;
    for (int v = 0; v < 3; ++v) { g1.coef[v] = V[v].coef1; g1.h[v] = nf16; }
    gather3<<<dim3(ng, 3), 256, 0, stream>>>(g1);

    GemmArgs m1;
    m1.T = T3; m1.hout = h1b; m1.M = M; m1.relu = 1; m1.Tvs = Tvs; m1.hovs = hvs;
    for (int v = 0; v < 3; ++v) { m1.hin[v] = nf16; m1.WT[v] = WT1[v]; m1.bias[v] = V[v].bias1; }
    gemm_layer<<<dim3(gxL, 3), 512, 0, stream>>>(m1);

    // ---- layer 2 gather ----
    GatherArgs g2 = g1;
    for (int v = 0; v < 3; ++v) { g2.coef[v] = V[v].coef2; g2.h[v] = h1b + (size_t)v * hvs; }
    gather3<<<dim3(ng, 3), 256, 0, stream>>>(g2);

    // ---- fused layer2 + fusion ----
    L2FArgs l2;
    l2.T = T3; l2.h1 = h1b; l2.bias = bias_o; l2.out = outF;
    l2.M = M; l2.Tvs = Tvs; l2.hvs = hvs;
    for (int v = 0; v < 3; ++v) l2.W2F[v] = W2F[v];
    gemm_l2f<<<gxL, 512, 0, stream>>>(l2);
}

// Round 18
// 285.240 us; speedup vs baseline: 1.0525x; 1.0192x over previous
//
#include <hip/hip_runtime.h>
#include <hip/hip_bf16.h>
#include <stdint.h>

typedef _Float16 f16x8 __attribute__((ext_vector_type(8)));
typedef _Float16 f16x2 __attribute__((ext_vector_type(2)));
typedef float f32x4 __attribute__((ext_vector_type(4)));

// All fp16 activation/weight buffers are stored ROW-SWIZZLED: within each
// 128-col chunk, element col c of row r lives at c ^ ((r&7)<<3).

__device__ __forceinline__ void gll16(const _Float16* g, _Float16* l) {
    __builtin_amdgcn_global_load_lds(
        (const __attribute__((address_space(1))) void*)g,
        (__attribute__((address_space(3))) void*)l, 16, 0, 0);
}

// ------------- weight prep: f32 [i][o] 128x128 tile -> fp16 dst[o][i^swz(o)] -------------
struct PrepDesc { const float* src; _Float16* dst; int dstride; };
struct PrepArgs { PrepDesc d[33]; };

__global__ __launch_bounds__(256) void prep_weights(PrepArgs args) {
    __shared__ _Float16 lds[128 * 129];
    const PrepDesc de = args.d[blockIdx.x];
    int t = threadIdx.x;
    for (int q = 0; q < 64; ++q) {
        int li = t + q * 256;            // linear over src [i][o]
        int i = li >> 7, o = li & 127;
        lds[o * 129 + i] = (_Float16)de.src[li];
    }
    __syncthreads();
    for (int q = 0; q < 64; ++q) {
        int lo = t + q * 256;            // linear over dst [o][i]
        int o = lo >> 7, i = lo & 127;
        de.dst[(size_t)o * de.dstride + (i ^ ((o & 7) << 3))] = lds[o * 129 + i];
    }
}

// ---- fold: W2F[v][of][640] = sum_o2 A_c[i][o2] * F_v[o2][of], fp16 swizzled output ----
// grid (6,3): c<5 = GEMM tiles; block (5,0) computes the folded bias.
struct FoldArgs {
    const float* bases2[3];
    const float* loopw2[3];
    const float* fw;           // [384][128]
    const float* b2[3];        // [128] each
    const float* fb;           // [128]
    _Float16* W2F[3];          // [128 of][640 k]
    float* bias_out;           // [128]
};

__global__ __launch_bounds__(256) void fold_w2f(FoldArgs fa) {
    int c = blockIdx.x, v = blockIdx.y, t = threadIdx.x;
    if (c == 5) {
        // bias fold: only (5,0) active; 256 threads = 2 per of
        if (v != 0) return;
        __shared__ float s[256];
        int of = t & 127, half = t >> 7;
        float acc = 0.f;
        for (int j = half * 192; j < (half + 1) * 192; ++j)
            acc += fa.b2[j >> 7][j & 127] * fa.fw[(size_t)j * 128 + of];
        s[t] = acc;
        __syncthreads();
        if (half == 0) fa.bias_out[of] = fa.fb[of] + s[of] + s[of + 128];
        return;
    }
    __shared__ _Float16 As[128 * 136];
    __shared__ _Float16 Bs[128 * 136];
    const float* A = (c < 4) ? fa.bases2[v] + (size_t)c * 16384 : fa.loopw2[v];
    for (int q = 0; q < 64; ++q) {
        int li = t + q * 256;            // i*128 + o2
        int i = li >> 7, o2 = li & 127;
        As[i * 136 + o2] = (_Float16)A[li];
    }
    for (int q = 0; q < 64; ++q) {
        int li = t + q * 256;            // o2*128 + of
        int o2 = li >> 7, of = li & 127;
        Bs[of * 136 + o2] = (_Float16)fa.fw[(size_t)(v * 128 + o2) * 128 + of];
    }
    __syncthreads();

    int wid = t >> 6, lane = t & 63;
    int wr = (wid >> 1) * 64;
    int wc = (wid & 1) * 64;
    int lm = lane & 15;
    int lk = (lane >> 4) * 8;

    f32x4 acc[4][4] = {};
    for (int ks = 0; ks < 4; ++ks) {
        f16x8 a[4], b[4];
        for (int mi = 0; mi < 4; ++mi)
            a[mi] = *(const f16x8*)(As + (wr + mi * 16 + lm) * 136 + ks * 32 + lk);
        for (int ni = 0; ni < 4; ++ni)
            b[ni] = *(const f16x8*)(Bs + (wc + ni * 16 + lm) * 136 + ks * 32 + lk);
        for (int mi = 0; mi < 4; ++mi)
            for (int ni = 0; ni < 4; ++ni)
                acc[mi][ni] = __builtin_amdgcn_mfma_f32_16x16x32_f16(a[mi], b[ni], acc[mi][ni], 0, 0, 0);
    }

    int rbase = (lane >> 4) * 4;
    _Float16* dst = fa.W2F[v];
    for (int mi = 0; mi < 4; ++mi) {
        for (int j = 0; j < 4; ++j) {
            int i = wr + mi * 16 + rbase + j;
            for (int ni = 0; ni < 4; ++ni) {
                int of = wc + ni * 16 + lm;
                dst[(size_t)of * 640 + c * 128 + (i ^ ((of & 7) << 3))] = (_Float16)acc[mi][ni][j];
            }
        }
    }
}

// ---------------- f32 -> fp16 convert (row-swizzled output) ----------------
__global__ __launch_bounds__(256) void f32_to_f16(const float* __restrict__ in,
                                                  _Float16* __restrict__ out, int n4) {
    int i = blockIdx.x * 256 + threadIdx.x;
    if (i >= n4) return;
    float4 v = *((const float4*)in + i);
    int n = i >> 5;
    int c = (i & 31) * 4;
    int cs = c ^ ((n & 7) << 3);
    f16x2 a, b;
    a[0] = (_Float16)v.x; a[1] = (_Float16)v.y;
    b[0] = (_Float16)v.z; b[1] = (_Float16)v.w;
    _Float16* o = out + (size_t)n * 128 + cs;
    *(f16x2*)o = a;
    *(f16x2*)(o + 2) = b;
}

// ---------------- CSR build via block-local counting sort (no global atomics) ----------
struct EdgeArgs {
    const int* src[3]; const int* dst[3]; const int* rel[3];
    int E[3]; int N;
};

__global__ __launch_bounds__(256) void bhist(EdgeArgs ea, int* __restrict__ hmat, int nbk) {
    __shared__ int cnt[256];
    int v = blockIdx.y, blk = blockIdx.x, t = threadIdx.x;
    cnt[t] = 0;
    __syncthreads();
    int E = ea.E[v];
    const int* dst = ea.dst[v];
    int chunk = (E + 63) >> 6;
    int e0 = blk * chunk;
    int e1 = min(e0 + chunk, E);
    for (int e = e0 + t; e < e1; e += 256)
        atomicAdd(&cnt[dst[e] >> 8], 1);
    __syncthreads();
    if (t < nbk)
        hmat[((size_t)v * nbk + t) * 64 + blk] = cnt[t];
}

// per-2048-chunk exclusive scan; global prefix applied by consumers via bsum
__global__ __launch_bounds__(256) void scan1_kernel(const int* __restrict__ deg,
                                                    int* __restrict__ off,
                                                    int* __restrict__ bsum, int n) {
    __shared__ int s[256];
    int b = blockIdx.x, t = threadIdx.x;
    int base = b * 2048 + t * 8;
    int v[8]; int sum = 0;
    for (int j = 0; j < 8; ++j) {
        int x = (base + j < n) ? deg[base + j] : 0;
        v[j] = sum;
        sum += x;
    }
    s[t] = sum;
    __syncthreads();
    for (int st = 1; st < 256; st <<= 1) {
        int y = (t >= st) ? s[t - st] : 0;
        __syncthreads();
        s[t] += y;
        __syncthreads();
    }
    int texcl = t ? s[t - 1] : 0;
    if (t == 255) bsum[b] = s[255];
    for (int j = 0; j < 8; ++j)
        if (base + j < n) off[base + j] = texcl + v[j];
}

__device__ __forceinline__ int chunk_pref(const int* bsum, int flat) {
    int ck = flat >> 11;
    int p = 0;
    for (int j = 0; j < ck; ++j) p += bsum[j];
    return p;
}

// mid record: src (16b) | rel (4b @16) | dst&255 (8b @20)
__global__ __launch_bounds__(256) void bscat(EdgeArgs ea, const int* __restrict__ smat,
                                             const int* __restrict__ bsum,
                                             int* __restrict__ mid, int nbk) {
    __shared__ int cur[256];
    int v = blockIdx.y, blk = blockIdx.x, t = threadIdx.x;
    if (t < nbk) {
        int flat = ((size_t)v * nbk + t) * 64 + blk;
        cur[t] = smat[flat] + chunk_pref(bsum, flat);
    }
    __syncthreads();
    int E = ea.E[v];
    const int* src = ea.src[v];
    const int* dst = ea.dst[v];
    const int* rel = ea.rel[v];
    int chunk = (E + 63) >> 6;
    int e0 = blk * chunk;
    int e1 = min(e0 + chunk, E);
    for (int e = e0 + t; e < e1; e += 256) {
        int d = dst[e];
        int pos = atomicAdd(&cur[d >> 8], 1);
        mid[pos] = src[e] | (rel[e] << 16) | ((d & 255) << 20);
    }
}

__global__ __launch_bounds__(256) void bfinal(const int* __restrict__ smat,
                                              const int* __restrict__ bsum,
                                              const int* __restrict__ mid,
                                              int* __restrict__ off3,
                                              int* __restrict__ packed3,
                                              int M, int nbk, int Etot) {
    __shared__ int cnt[256];
    __shared__ int s[256];
    __shared__ int cur[256];
    int bk = blockIdx.x, v = blockIdx.y, t = threadIdx.x;
    int flat0 = (v * nbk + bk) * 64;
    int flat1 = flat0 + 64;
    int nflat = 3 * nbk * 64;
    int start = smat[flat0] + chunk_pref(bsum, flat0);
    int end   = (flat1 < nflat) ? smat[flat1] + chunk_pref(bsum, flat1) : Etot;
    cnt[t] = 0;
    __syncthreads();
    for (int i = start + t; i < end; i += 256)
        atomicAdd(&cnt[(mid[i] >> 20) & 255], 1);
    __syncthreads();
    s[t] = cnt[t];
    __syncthreads();
    for (int st = 1; st < 256; st <<= 1) {
        int y = (t >= st) ? s[t - st] : 0;
        __syncthreads();
        s[t] += y;
        __syncthreads();
    }
    int excl = t ? s[t - 1] : 0;
    int node = (bk << 8) + t;
    if (node < M) off3[(size_t)v * M + node] = start + excl;
    cur[t] = start + excl;
    __syncthreads();
    for (int i = start + t; i < end; i += 256) {
        int m = mid[i];
        int pos = atomicAdd(&cur[(m >> 20) & 255], 1);
        packed3[pos] = (m & 0xFFFF) | (((m >> 16) & 15) << 20);
    }
    if (v == 2 && bk == nbk - 1 && t == 0) off3[(size_t)3 * M] = Etot;
}

// ---- gather: T[v][d][b][:] += coef*h[src]; 2 nodes per wave, interleaved 2+2 batches ----
struct GatherArgs {
    const int* off3;
    const int* packed3;
    const float* coef[3];     // [R][4]
    const _Float16* h[3];     // [N][128] swizzled
    _Float16* T;              // [N][4][128] swizzled per node
    int N; size_t Tvs;
};

__global__ __launch_bounds__(256) void gather3(GatherArgs g) {
    int v = blockIdx.y;
    int wid = threadIdx.x >> 6;
    int lane = threadIdx.x & 63;
    int nodeA = blockIdx.x * 8 + wid * 2;
    if (nodeA >= g.N) return;
    int nodeB = nodeA + 1;
    bool hasB = nodeB < g.N;

    const int* off = g.off3 + (size_t)v * g.N;
    const float* coef = g.coef[v];
    const _Float16* h = g.h[v];
    _Float16* T = g.T + (size_t)v * g.Tvs;

    int iA = __builtin_amdgcn_readfirstlane(off[nodeA]);
    int eA = __builtin_amdgcn_readfirstlane(off[nodeA + 1]);
    int iB = eA;
    int eB = hasB ? __builtin_amdgcn_readfirstlane(off[nodeB + 1]) : eA;

    float accA[8] = {}, accB[8] = {};

    auto edge1 = [&](int p, float* acc) {
        int s = p & 0xFFFFF, r = p >> 20;
        uint32_t q = ((const uint32_t*)(h + (size_t)s * 128))[lane ^ ((s & 7) << 2)];
        float4 c = *(const float4*)(coef + (size_t)r * 4);
        f16x2 u = __builtin_bit_cast(f16x2, q);
        float lo = (float)u[0], hi = (float)u[1];
        acc[0] += c.x * lo;  acc[1] += c.x * hi;
        acc[2] += c.y * lo;  acc[3] += c.y * hi;
        acc[4] += c.z * lo;  acc[5] += c.z * hi;
        acc[6] += c.w * lo;  acc[7] += c.w * hi;
    };

    for (; iA + 1 < eA && iB + 1 < eB; iA += 2, iB += 2) {
        int pA0 = __builtin_amdgcn_readfirstlane(g.packed3[iA]);
        int pA1 = __builtin_amdgcn_readfirstlane(g.packed3[iA + 1]);
        int pB0 = __builtin_amdgcn_readfirstlane(g.packed3[iB]);
        int pB1 = __builtin_amdgcn_readfirstlane(g.packed3[iB + 1]);
        int sA0 = pA0 & 0xFFFFF, sA1 = pA1 & 0xFFFFF;
        int sB0 = pB0 & 0xFFFFF, sB1 = pB1 & 0xFFFFF;
        uint32_t qA0 = ((const uint32_t*)(h + (size_t)sA0 * 128))[lane ^ ((sA0 & 7) << 2)];
        uint32_t qA1 = ((const uint32_t*)(h + (size_t)sA1 * 128))[lane ^ ((sA1 & 7) << 2)];
        uint32_t qB0 = ((const uint32_t*)(h + (size_t)sB0 * 128))[lane ^ ((sB0 & 7) << 2)];
        uint32_t qB1 = ((const uint32_t*)(h + (size_t)sB1 * 128))[lane ^ ((sB1 & 7) << 2)];
        float4 cA0 = *(const float4*)(coef + (size_t)(pA0 >> 20) * 4);
        float4 cA1 = *(const float4*)(coef + (size_t)(pA1 >> 20) * 4);
        float4 cB0 = *(const float4*)(coef + (size_t)(pB0 >> 20) * 4);
        float4 cB1 = *(const float4*)(coef + (size_t)(pB1 >> 20) * 4);
        f16x2 u;
        float lo, hi;
        u = __builtin_bit_cast(f16x2, qA0); lo = (float)u[0]; hi = (float)u[1];
        accA[0] += cA0.x * lo; accA[1] += cA0.x * hi; accA[2] += cA0.y * lo; accA[3] += cA0.y * hi;
        accA[4] += cA0.z * lo; accA[5] += cA0.z * hi; accA[6] += cA0.w * lo; accA[7] += cA0.w * hi;
        u = __builtin_bit_cast(f16x2, qA1); lo = (float)u[0]; hi = (float)u[1];
        accA[0] += cA1.x * lo; accA[1] += cA1.x * hi; accA[2] += cA1.y * lo; accA[3] += cA1.y * hi;
        accA[4] += cA1.z * lo; accA[5] += cA1.z * hi; accA[6] += cA1.w * lo; accA[7] += cA1.w * hi;
        u = __builtin_bit_cast(f16x2, qB0); lo = (float)u[0]; hi = (float)u[1];
        accB[0] += cB0.x * lo; accB[1] += cB0.x * hi; accB[2] += cB0.y * lo; accB[3] += cB0.y * hi;
        accB[4] += cB0.z * lo; accB[5] += cB0.z * hi; accB[6] += cB0.w * lo; accB[7] += cB0.w * hi;
        u = __builtin_bit_cast(f16x2, qB1); lo = (float)u[0]; hi = (float)u[1];
        accB[0] += cB1.x * lo; accB[1] += cB1.x * hi; accB[2] += cB1.y * lo; accB[3] += cB1.y * hi;
        accB[4] += cB1.z * lo; accB[5] += cB1.z * hi; accB[6] += cB1.w * lo; accB[7] += cB1.w * hi;
    }
    for (; iA + 1 < eA; iA += 2) {
        int p0 = __builtin_amdgcn_readfirstlane(g.packed3[iA]);
        int p1 = __builtin_amdgcn_readfirstlane(g.packed3[iA + 1]);
        edge1(p0, accA); edge1(p1, accA);
    }
    for (; iA < eA; ++iA)
        edge1(__builtin_amdgcn_readfirstlane(g.packed3[iA]), accA);
    for (; iB + 1 < eB; iB += 2) {
        int p0 = __builtin_amdgcn_readfirstlane(g.packed3[iB]);
        int p1 = __builtin_amdgcn_readfirstlane(g.packed3[iB + 1]);
        edge1(p0, accB); edge1(p1, accB);
    }
    for (; iB < eB; ++iB)
        edge1(__builtin_amdgcn_readfirstlane(g.packed3[iB]), accB);

    {
        int cs = (2 * lane) ^ ((nodeA & 7) << 3);
        _Float16* tb = T + (size_t)nodeA * 512 + cs;
        for (int b = 0; b < 4; ++b) {
            f16x2 o; o[0] = (_Float16)accA[2 * b]; o[1] = (_Float16)accA[2 * b + 1];
            *(f16x2*)(tb + b * 128) = o;
        }
    }
    if (hasB) {
        int cs = (2 * lane) ^ ((nodeB & 7) << 3);
        _Float16* tb = T + (size_t)nodeB * 512 + cs;
        for (int b = 0; b < 4; ++b) {
            f16x2 o; o[0] = (_Float16)accB[2 * b]; o[1] = (_Float16)accB[2 * b + 1];
            *(f16x2*)(tb + b * 128) = o;
        }
    }
}

// ---- layer-1 GEMM: h1 = relu([T | h] @ WT^T + bias), K=640, BM=64, swizzled fp16 out ----
struct GemmArgs {
    const _Float16* T;        // base; +v*Tvs (swizzled)
    const _Float16* hin[3];   // swizzled
    const _Float16* WT[3];    // [128][640] swizzled per 128-chunk
    const float* bias[3];
    _Float16* hout;           // base; +v*hovs (written swizzled)
    int M; int relu; size_t Tvs; size_t hovs;
};

__global__ __launch_bounds__(512) void gemm_layer(GemmArgs ga) {
    __shared__ _Float16 As[64 * 128];
    __shared__ _Float16 Bs[128 * 128];
    int v = blockIdx.y;
    const _Float16* Tb  = ga.T + (size_t)v * ga.Tvs;
    const _Float16* hin = ga.hin[v];
    const _Float16* BT  = ga.WT[v];
    const float* bias   = ga.bias[v];
    _Float16* out       = ga.hout + (size_t)v * ga.hovs;
    int M = ga.M;

    int tid = threadIdx.x;
    int m0 = blockIdx.x * 64;
    int wid = tid >> 6, lane = tid & 63;
    int wr = (wid >> 2) * 32;
    int wc = (wid & 3) * 32;
    int lm = lane & 15;
    int lk = (lane >> 4) * 8;
    int xm = (lm & 7) << 3;

    f32x4 acc[2][2] = {};

    for (int kb = 0; kb < 5; ++kb) {
        const _Float16* Asrc; size_t astride;
        if (kb < 4) { Asrc = Tb + (size_t)kb * 128; astride = 512; }
        else        { Asrc = hin;                   astride = 128; }
        for (int q = 0; q < 2; ++q) {
            int li = tid + q * 512;
            int r = li >> 4;
            int c = (li & 15) << 3;
            int gr = m0 + r; if (gr >= M) gr = M - 1;
            gll16(Asrc + (size_t)gr * astride + c, As + (size_t)li * 8);
        }
        for (int q = 0; q < 4; ++q) {
            int li = tid + q * 512;
            gll16(BT + (size_t)(li >> 4) * 640 + kb * 128 + ((li & 15) << 3),
                  Bs + (size_t)li * 8);
        }
        __syncthreads();

        for (int ks = 0; ks < 4; ++ks) {
            int ac = (ks * 32 + lk) ^ xm;
            f16x8 a[2], b[2];
            for (int mi = 0; mi < 2; ++mi)
                a[mi] = *(const f16x8*)(As + (wr + mi * 16 + lm) * 128 + ac);
            for (int ni = 0; ni < 2; ++ni)
                b[ni] = *(const f16x8*)(Bs + (wc + ni * 16 + lm) * 128 + ac);
            for (int mi = 0; mi < 2; ++mi)
                for (int ni = 0; ni < 2; ++ni)
                    acc[mi][ni] = __builtin_amdgcn_mfma_f32_16x16x32_f16(a[mi], b[ni], acc[mi][ni], 0, 0, 0);
        }
        __syncthreads();
    }

    int rbase = (lane >> 4) * 4;
    for (int mi = 0; mi < 2; ++mi) {
        for (int j = 0; j < 4; ++j) {
            int gr = m0 + wr + mi * 16 + rbase + j;
            if (gr >= M) continue;
            int rs = (gr & 7) << 3;
            for (int ni = 0; ni < 2; ++ni) {
                int col = wc + ni * 16 + lm;
                float val = acc[mi][ni][j] + bias[col];
                if (ga.relu) val = fmaxf(val, 0.f);
                out[(size_t)gr * 128 + (col ^ rs)] = (_Float16)val;
            }
        }
    }
}

// ---- fused layer2+fusion GEMM: out_f32 = sum_v [T_v | h1_v] @ W2F_v + bias_out ----
struct L2FArgs {
    const _Float16* T;        // T3 base (swizzled); +v*Tvs
    const _Float16* h1;       // h1b base (swizzled); +v*hvs
    const _Float16* W2F[3];   // [128 of][640 k] swizzled per 128-chunk
    const float* bias;        // folded bias [128]
    float* out; int M; size_t Tvs; size_t hvs;
};

__global__ __launch_bounds__(512) void gemm_l2f(L2FArgs ga) {
    __shared__ _Float16 As[64 * 128];
    __shared__ _Float16 Bs[128 * 128];
    int M = ga.M;
    int tid = threadIdx.x;
    int m0 = blockIdx.x * 64;
    int wid = tid >> 6, lane = tid & 63;
    int wr = (wid >> 2) * 32;
    int wc = (wid & 3) * 32;
    int lm = lane & 15;
    int lk = (lane >> 4) * 8;
    int xm = (lm & 7) << 3;

    f32x4 acc[2][2] = {};

    for (int v = 0; v < 3; ++v) {
        const _Float16* Tb = ga.T + (size_t)v * ga.Tvs;
        const _Float16* hb = ga.h1 + (size_t)v * ga.hvs;
        const _Float16* BT = ga.W2F[v];
        for (int kb = 0; kb < 5; ++kb) {
            const _Float16* Asrc; size_t astride;
            if (kb < 4) { Asrc = Tb + (size_t)kb * 128; astride = 512; }
            else        { Asrc = hb;                    astride = 128; }
            for (int q = 0; q < 2; ++q) {
                int li = tid + q * 512;
                int r = li >> 4;
                int c = (li & 15) << 3;
                int gr = m0 + r; if (gr >= M) gr = M - 1;
                gll16(Asrc + (size_t)gr * astride + c, As + (size_t)li * 8);
            }
            for (int q = 0; q < 4; ++q) {
                int li = tid + q * 512;
                gll16(BT + (size_t)(li >> 4) * 640 + kb * 128 + ((li & 15) << 3),
                      Bs + (size_t)li * 8);
            }
            __syncthreads();

            for (int ks = 0; ks < 4; ++ks) {
                int ac = (ks * 32 + lk) ^ xm;
                f16x8 a[2], b[2];
                for (int mi = 0; mi < 2; ++mi)
                    a[mi] = *(const f16x8*)(As + (wr + mi * 16 + lm) * 128 + ac);
                for (int ni = 0; ni < 2; ++ni)
                    b[ni] = *(const f16x8*)(Bs + (wc + ni * 16 + lm) * 128 + ac);
                for (int mi = 0; mi < 2; ++mi)
                    for (int ni = 0; ni < 2; ++ni)
                        acc[mi][ni] = __builtin_amdgcn_mfma_f32_16x16x32_f16(a[mi], b[ni], acc[mi][ni], 0, 0, 0);
            }
            __syncthreads();
        }
    }

    int rbase = (lane >> 4) * 4;
    for (int mi = 0; mi < 2; ++mi) {
        for (int j = 0; j < 4; ++j) {
            int gr = m0 + wr + mi * 16 + rbase + j;
            if (gr >= M) continue;
            for (int ni = 0; ni < 2; ++ni) {
                int col = wc + ni * 16 + lm;
                ga.out[(size_t)gr * 128 + col] = acc[mi][ni][j] + ga.bias[col];
            }
        }
    }
}

// ---------------- host launch ----------------
extern "C" void kernel_launch(void* const* d_in, const int* in_sizes, int n_in,
                              void* d_out, int out_size, void* d_ws, size_t ws_size,
                              hipStream_t stream) {
    const int D = 128;
    const int M = in_sizes[0] / D;

    struct ViewIn {
        const int *src, *dst, *rel;
        const float *bases1, *coef1, *loopw1, *bias1;
        const float *bases2, *coef2, *loopw2, *bias2;
        int E;
    } V[3];
    int idx = 1;
    for (int v = 0; v < 3; ++v) {
        V[v].src    = (const int*)d_in[idx + 0];
        V[v].dst    = (const int*)d_in[idx + 1];
        V[v].rel    = (const int*)d_in[idx + 2];
        V[v].bases1 = (const float*)d_in[idx + 3];
        V[v].coef1  = (const float*)d_in[idx + 4];
        V[v].loopw1 = (const float*)d_in[idx + 5];
        V[v].bias1  = (const float*)d_in[idx + 6];
        V[v].bases2 = (const float*)d_in[idx + 7];
        V[v].coef2  = (const float*)d_in[idx + 8];
        V[v].loopw2 = (const float*)d_in[idx + 9];
        V[v].bias2  = (const float*)d_in[idx + 10];
        V[v].E      = in_sizes[idx + 0];
        idx += 11;
    }
    const float* fusion_w = (const float*)d_in[idx];
    const float* fusion_b = (const float*)d_in[idx + 1];
    int Etot = V[0].E + V[1].E + V[2].E;

    int nbk = (M + 255) >> 8;
    int nsc = 3 * nbk * 64;

    // ---- workspace carve ----
    char* w = (char*)d_ws;
    auto alloc = [&](size_t bytes) -> char* {
        char* p = w; w += (bytes + 255) & ~(size_t)255; return p;
    };
    _Float16* nf16 = (_Float16*)alloc((size_t)M * 128 * 2);
    _Float16* wts  = (_Float16*)alloc((size_t)(3 * 81920) * 2);
    _Float16* w2f  = (_Float16*)alloc((size_t)(3 * 81920) * 2);
    float* bias_o  = (float*)alloc(128 * 4);
    int* hmat      = (int*)alloc((size_t)nsc * 4);
    int* smat      = (int*)alloc(((size_t)nsc + 1) * 4);
    int* bsum      = (int*)alloc(512);
    int* off3      = (int*)alloc(((size_t)3 * M + 1) * 4);
    int* mid       = (int*)alloc((size_t)Etot * 4);
    int* packed3   = (int*)alloc((size_t)Etot * 4);
    _Float16* T3   = (_Float16*)alloc((size_t)3 * M * 512 * 2);
    _Float16* h1b  = (_Float16*)alloc((size_t)3 * M * 128 * 2);

    _Float16 *WT1[3], *W2F[3];
    for (int v = 0; v < 3; ++v) {
        WT1[v] = wts + (size_t)v * 81920;
        W2F[v] = w2f + (size_t)v * 81920;
    }

    // ---- prep: layer-1 weight transposes (15 tiles) ----
    PrepArgs pa;
    int t = 0;
    for (int v = 0; v < 3; ++v) {
        for (int b = 0; b < 4; ++b) {
            pa.d[t].src = V[v].bases1 + (size_t)b * 16384;
            pa.d[t].dst = WT1[v] + (size_t)b * 128;
            pa.d[t].dstride = 640; ++t;
        }
        pa.d[t].src = V[v].loopw1;
        pa.d[t].dst = WT1[v] + 512;
        pa.d[t].dstride = 640; ++t;
    }
    prep_weights<<<t, 256, 0, stream>>>(pa);

    // ---- fold W2@F + bias (single dispatch) ----
    FoldArgs fo;
    for (int v = 0; v < 3; ++v) {
        fo.bases2[v] = V[v].bases2;
        fo.loopw2[v] = V[v].loopw2;
        fo.W2F[v] = W2F[v];
        fo.b2[v] = V[v].bias2;
    }
    fo.fw = fusion_w;
    fo.fb = fusion_b;
    fo.bias_out = bias_o;
    fold_w2f<<<dim3(6, 3), 256, 0, stream>>>(fo);

    int n4 = M * D / 4;
    f32_to_f16<<<(n4 + 255) / 256, 256, 0, stream>>>((const float*)d_in[0], nf16, n4);

    // ---- CSR build (block-local counting sort; scan prefix folded into consumers) ----
    EdgeArgs ea;
    for (int v = 0; v < 3; ++v) {
        ea.src[v] = V[v].src; ea.dst[v] = V[v].dst; ea.rel[v] = V[v].rel; ea.E[v] = V[v].E;
    }
    ea.N = M;
    int nsb = (nsc + 2047) / 2048;
    bhist<<<dim3(64, 3), 256, 0, stream>>>(ea, hmat, nbk);
    scan1_kernel<<<nsb, 256, 0, stream>>>(hmat, smat, bsum, nsc);
    bscat<<<dim3(64, 3), 256, 0, stream>>>(ea, smat, bsum, mid, nbk);
    bfinal<<<dim3(nbk, 3), 256, 0, stream>>>(smat, bsum, mid, off3, packed3, M, nbk, Etot);

    int ng  = (M + 7) / 8;
    int gxL = (M + 63) / 64;
    size_t Tvs = (size_t)M * 512;
    size_t hvs = (size_t)M * 128;
    float* outF = (float*)d_out;

    // ---- layer 1 ----
    GatherArgs g1;
    g1.off3 = off3; g1.packed3 = packed3; g1.T = T3; g1.N = M; g1.Tvs = Tvs;
    for (int v = 0; v < 3; ++v) { g1.coef[v] = V[v].coef1; g1.h[v] = nf16; }
    gather3<<<dim3(ng, 3), 256, 0, stream>>>(g1);

    GemmArgs m1;
    m1.T = T3; m1.hout = h1b; m1.M = M; m1.relu = 1; m1.Tvs = Tvs; m1.hovs = hvs;
    for (int v = 0; v < 3; ++v) { m1.hin[v] = nf16; m1.WT[v] = WT1[v]; m1.bias[v] = V[v].bias1; }
    gemm_layer<<<dim3(gxL, 3), 512, 0, stream>>>(m1);

    // ---- layer 2 gather ----
    GatherArgs g2 = g1;
    for (int v = 0; v < 3; ++v) { g2.coef[v] = V[v].coef2; g2.h[v] = h1b + (size_t)v * hvs; }
    gather3<<<dim3(ng, 3), 256, 0, stream>>>(g2);

    // ---- fused layer2 + fusion ----
    L2FArgs l2;
    l2.T = T3; l2.h1 = h1b; l2.bias = bias_o; l2.out = outF;
    l2.M = M; l2.Tvs = Tvs; l2.hvs = hvs;
    for (int v = 0; v < 3; ++v) l2.W2F[v] = W2F[v];
    gemm_l2f<<<gxL, 512, 0, stream>>>(l2);
}